// Round 7
// baseline (466.764 us; speedup 1.0000x reference)
//
#include <hip/hip_runtime.h>

// SelfAttention: B=4 S=2048 D=1024 H=16 HD=64, causal, fp32 in/out, bf16 MFMA compute.
// R6: attn occupancy fix — R5's exp2 rewrite pushed VGPR 64->68, crossing the
// waves-halve-at-64 cliff (8->4 blocks/CU, attn 103->122us). Force
// __launch_bounds__(256,8) (=> <=64 VGPR), adopt v_perm bf16 packing (lane-local,
// deterministic; frees the f2bf chains). Merge 4 transpose launches into one.
// Structure otherwise frozen at R5 (R3-proven skeleton + exp2 domain).

typedef __attribute__((ext_vector_type(8))) short short8_t;
typedef __attribute__((ext_vector_type(4))) short short4_t;
typedef __attribute__((ext_vector_type(4))) float float4_t;
typedef __attribute__((ext_vector_type(2))) unsigned int uint2_t;

constexpr int Bz = 4, Sq = 2048, Dm = 1024, NH = 16, HD = 64;
constexpr int LDSPITCH = 72;

#define GLOAD_LDS16(g, l)                                                      \
  __builtin_amdgcn_global_load_lds(                                            \
      (const __attribute__((address_space(1))) unsigned int*)(g),              \
      (__attribute__((address_space(3))) unsigned int*)(l), 16, 0, 0)

__device__ __forceinline__ unsigned short f2bf(float f) {
  unsigned u = __builtin_bit_cast(unsigned, f);
  u += 0x7fffu + ((u >> 16) & 1u);
  return (unsigned short)(u >> 16);
}

__global__ __launch_bounds__(256) void cast_x_kernel(const float* __restrict__ x,
                                                     unsigned short* __restrict__ xb) {
  size_t i = (size_t)blockIdx.x * 256 + threadIdx.x;
  float4 v = ((const float4*)x)[i];
  ushort4 o;
  o.x = f2bf(v.x); o.y = f2bf(v.y); o.z = f2bf(v.z); o.w = f2bf(v.w);
  ((ushort4*)xb)[i] = o;
}

// All four W [K=1024][N=1024] fp32 -> WT [N][K] bf16 in one launch. grid (16,16,4).
// z==0 (Wq) carries 0.125*log2e.
__global__ __launch_bounds__(256) void transpose_w_kernel(
    const float* __restrict__ Wq, const float* __restrict__ Wk,
    const float* __restrict__ Wv, const float* __restrict__ Wo,
    unsigned short* __restrict__ wqT, unsigned short* __restrict__ wkT,
    unsigned short* __restrict__ wvT, unsigned short* __restrict__ woT) {
  __shared__ float tile[64][65];
  int zz = blockIdx.z;
  const float* W = zz == 0 ? Wq : (zz == 1 ? Wk : (zz == 2 ? Wv : Wo));
  unsigned short* WT = zz == 0 ? wqT : (zz == 1 ? wkT : (zz == 2 ? wvT : woT));
  float scale = zz == 0 ? 0.125f * 1.4426950408889634f : 1.0f;
  int n0 = blockIdx.x * 64, k0 = blockIdx.y * 64;
  int tx = threadIdx.x & 63, ty = threadIdx.x >> 6;
#pragma unroll
  for (int i = 0; i < 16; ++i) {
    int r = i * 4 + ty;
    tile[r][tx] = W[(size_t)(k0 + r) * Dm + n0 + tx];
  }
  __syncthreads();
#pragma unroll
  for (int i = 0; i < 16; ++i) {
    int r = i * 4 + ty;
    WT[(size_t)(n0 + r) * Dm + k0 + tx] = f2bf(tile[tx][r] * scale);
  }
}

// m97-style main loop: 128x128 tile, BK=64, glds width=16, unpadded LDS.
__device__ __forceinline__ void gemm_mainloop(const unsigned short* __restrict__ A,
                                              const unsigned short* __restrict__ BT,
                                              int m0, int n0,
                                              unsigned short* lA, unsigned short* lB,
                                              float4_t acc[4][4]) {
  const int tid = threadIdx.x;
  const int lane = tid & 63, lr = lane & 15, quad = lane >> 4;
  const int wave = tid >> 6;
  const int mw = (wave >> 1) * 64, nw = (wave & 1) * 64;
  const int srow = tid >> 3;
  const int scol = (tid & 7) * 8;
  const unsigned short* ga = A + (size_t)(m0 + srow) * Dm + scol;
  const unsigned short* gb = BT + (size_t)(n0 + srow) * Dm + scol;
  unsigned short* la = lA + tid * 8;
  unsigned short* lb = lB + tid * 8;

  for (int k0 = 0; k0 < Dm; k0 += 64) {
    __syncthreads();
#pragma unroll
    for (int iss = 0; iss < 4; ++iss) {
      GLOAD_LDS16(ga + (size_t)iss * 32 * Dm + k0, la + iss * 32 * 64);
      GLOAD_LDS16(gb + (size_t)iss * 32 * Dm + k0, lb + iss * 32 * 64);
    }
    __syncthreads();
#pragma unroll
    for (int kk = 0; kk < 2; ++kk) {
      short8_t a[4], b[4];
#pragma unroll
      for (int i = 0; i < 4; ++i)
        a[i] = *(const short8_t*)(lA + (mw + i * 16 + lr) * 64 + kk * 32 + quad * 8);
#pragma unroll
      for (int j = 0; j < 4; ++j)
        b[j] = *(const short8_t*)(lB + (nw + j * 16 + lr) * 64 + kk * 32 + quad * 8);
#pragma unroll
      for (int i = 0; i < 4; ++i)
#pragma unroll
        for (int j = 0; j < 4; ++j)
          acc[i][j] = __builtin_amdgcn_mfma_f32_16x16x32_bf16(a[i], b[j], acc[i][j], 0, 0, 0);
    }
  }
}

// QKV projections. Q,K -> [B,H,S,HD]; V -> TRANSPOSED [B,H,HD,S]. grid (8,64,3)
__global__ __launch_bounds__(256) void gemm_qkv_kernel(
    const unsigned short* __restrict__ xb,
    const unsigned short* __restrict__ wqT, const unsigned short* __restrict__ wkT,
    const unsigned short* __restrict__ wvT,
    unsigned short* __restrict__ qb, unsigned short* __restrict__ kb,
    unsigned short* __restrict__ vt) {
  __shared__ unsigned short lA[128 * 64];
  __shared__ unsigned short lB[128 * 64];
  const unsigned short* WT = blockIdx.z == 0 ? wqT : (blockIdx.z == 1 ? wkT : wvT);
  unsigned short* outb = blockIdx.z == 0 ? qb : (blockIdx.z == 1 ? kb : vt);
  bool isV = blockIdx.z == 2;
  int lane = threadIdx.x & 63, wave = threadIdx.x >> 6;
  int lr = lane & 15, quad = lane >> 4;
  int m0 = blockIdx.y * 128, n0 = blockIdx.x * 128;
  int m_base = m0 + (wave >> 1) * 64;
  int n_base = n0 + (wave & 1) * 64;
  float4_t z = {0.f, 0.f, 0.f, 0.f};
  float4_t acc[4][4];
#pragma unroll
  for (int i = 0; i < 4; ++i)
#pragma unroll
    for (int j = 0; j < 4; ++j) acc[i][j] = z;
  gemm_mainloop(xb, WT, m0, n0, lA, lB, acc);
  if (isV) {
#pragma unroll
    for (int i = 0; i < 4; ++i)
#pragma unroll
      for (int j = 0; j < 4; ++j) {
        int m = m_base + i * 16 + quad * 4;
        int n = n_base + j * 16 + lr;
        int b = m >> 11, s = m & (Sq - 1);
        int h = n >> 6, hd = n & (HD - 1);
        ushort4 pk;
        pk.x = f2bf(acc[i][j][0]); pk.y = f2bf(acc[i][j][1]);
        pk.z = f2bf(acc[i][j][2]); pk.w = f2bf(acc[i][j][3]);
        *(ushort4*)(outb + (((size_t)b * NH + h) * HD + hd) * Sq + s) = pk;
      }
  } else {
#pragma unroll
    for (int i = 0; i < 4; ++i)
#pragma unroll
      for (int j = 0; j < 4; ++j)
#pragma unroll
        for (int r = 0; r < 4; ++r) {
          int m = m_base + i * 16 + quad * 4 + r;
          int n = n_base + j * 16 + lr;
          int b = m >> 11, s = m & (Sq - 1);
          int h = n >> 6, hd = n & (HD - 1);
          outb[(((size_t)b * NH + h) * Sq + s) * HD + hd] = f2bf(acc[i][j][r]);
        }
  }
}

// Output projection: ao_bf16 [8192,1024] @ Wo -> fp32 out. grid (8,64)
__global__ __launch_bounds__(256) void gemm_out_kernel(
    const unsigned short* __restrict__ ao, const unsigned short* __restrict__ woT,
    float* __restrict__ out) {
  __shared__ unsigned short lA[128 * 64];
  __shared__ unsigned short lB[128 * 64];
  int lane = threadIdx.x & 63, wave = threadIdx.x >> 6;
  int lr = lane & 15, quad = lane >> 4;
  int m0 = blockIdx.y * 128, n0 = blockIdx.x * 128;
  int m_base = m0 + (wave >> 1) * 64;
  int n_base = n0 + (wave & 1) * 64;
  float4_t z = {0.f, 0.f, 0.f, 0.f};
  float4_t acc[4][4];
#pragma unroll
  for (int i = 0; i < 4; ++i)
#pragma unroll
    for (int j = 0; j < 4; ++j) acc[i][j] = z;
  gemm_mainloop(ao, woT, m0, n0, lA, lB, acc);
#pragma unroll
  for (int i = 0; i < 4; ++i)
#pragma unroll
    for (int j = 0; j < 4; ++j)
#pragma unroll
      for (int r = 0; r < 4; ++r) {
        int m = m_base + i * 16 + quad * 4 + r;
        int n = n_base + j * 16 + lr;
        out[(size_t)m * Dm + n] = acc[i][j][r];
      }
}

// Flash attention (R3-proven structure; exp2-domain; perm-pack).
// grid (16, B*H), block 256 (4 waves). Block does q-tiles {t, 31-t}.
// __launch_bounds__(256,8): pin 8 waves/EU => VGPR<=64 (R5 regressed to 68,
// crossing the waves-halve-at-64 occupancy cliff).
__global__ __launch_bounds__(256, 8) void attn_kernel(
    const unsigned short* __restrict__ qbuf, const unsigned short* __restrict__ kbuf,
    const unsigned short* __restrict__ vtbuf, unsigned short* __restrict__ ao) {
  __shared__ unsigned short lk[64 * LDSPITCH];
  __shared__ unsigned short lv[64 * LDSPITCH];
  int bh = blockIdx.y;
  int wave = threadIdx.x >> 6, lane = threadIdx.x & 63;
  int lcol = lane & 15, quad = lane >> 4;
  const unsigned short* Q = qbuf + (size_t)bh * Sq * HD;
  const unsigned short* K = kbuf + (size_t)bh * Sq * HD;
  const unsigned short* Vt = vtbuf + (size_t)bh * HD * Sq;
  int b = bh >> 4, h = bh & 15;
  int srow = threadIdx.x >> 2;
  int scol = (threadIdx.x & 3) * 16;
  float4_t z = {0.f, 0.f, 0.f, 0.f};

  for (int half = 0; half < 2; ++half) {
    int ti = half == 0 ? (int)blockIdx.x : 31 - (int)blockIdx.x;
    int q0w = ti * 64 + wave * 16;
    int q_global = q0w + lcol;
    short8_t qf0 = *(const short8_t*)(Q + (size_t)(q0w + lcol) * HD + quad * 8);
    short8_t qf1 = *(const short8_t*)(Q + (size_t)(q0w + lcol) * HD + 32 + quad * 8);
    float m_i = -INFINITY, l_i = 0.f;
    float4_t o[4];
#pragma unroll
    for (int f = 0; f < 4; ++f) o[f] = z;

    int nkt = ti + 1;
    for (int kt = 0; kt < nkt; ++kt) {
      int key0 = kt * 64;
      __syncthreads();
      {
        const unsigned short* kg = K + (size_t)(key0 + srow) * HD + scol;
        const unsigned short* vg = Vt + (size_t)srow * Sq + key0 + scol;
        unsigned short* kl = lk + srow * LDSPITCH + scol;
        unsigned short* vl = lv + srow * LDSPITCH + scol;
        *(short8_t*)(kl) = *(const short8_t*)(kg);
        *(short8_t*)(kl + 8) = *(const short8_t*)(kg + 8);
        *(short8_t*)(vl) = *(const short8_t*)(vg);
        *(short8_t*)(vl + 8) = *(const short8_t*)(vg + 8);
      }
      __syncthreads();

      bool need_mask = (key0 + 63 > q0w);
      float s[16];
      float tmax = -INFINITY;
#pragma unroll
      for (int s4 = 0; s4 < 4; ++s4) {
        short8_t kf0 = *(const short8_t*)(lk + (s4 * 16 + lcol) * LDSPITCH + quad * 8);
        short8_t kf1 = *(const short8_t*)(lk + (s4 * 16 + lcol) * LDSPITCH + 32 + quad * 8);
        float4_t st = z;
        st = __builtin_amdgcn_mfma_f32_16x16x32_bf16(kf0, qf0, st, 0, 0, 0);
        st = __builtin_amdgcn_mfma_f32_16x16x32_bf16(kf1, qf1, st, 0, 0, 0);
#pragma unroll
        for (int r = 0; r < 4; ++r) {
          float v = st[r];  // log2 domain (scale folded into Wq)
          if (need_mask && (key0 + s4 * 16 + quad * 4 + r > q_global)) v = -INFINITY;
          s[s4 * 4 + r] = v;
          tmax = fmaxf(tmax, v);
        }
      }
      tmax = fmaxf(tmax, __shfl_xor(tmax, 16, 64));
      tmax = fmaxf(tmax, __shfl_xor(tmax, 32, 64));
      float m_new = fmaxf(m_i, tmax);
      float alpha = __builtin_amdgcn_exp2f(m_i - m_new);  // first tile: exp2(-inf)=0
      float psum = 0.f;
      short4_t pf[4];
#pragma unroll
      for (int s4 = 0; s4 < 4; ++s4) {
        float p0 = __builtin_amdgcn_exp2f(s[s4 * 4 + 0] - m_new);
        float p1 = __builtin_amdgcn_exp2f(s[s4 * 4 + 1] - m_new);
        float p2 = __builtin_amdgcn_exp2f(s[s4 * 4 + 2] - m_new);
        float p3 = __builtin_amdgcn_exp2f(s[s4 * 4 + 3] - m_new);
        psum += (p0 + p1) + (p2 + p3);
        unsigned u0 = __builtin_bit_cast(unsigned, p0) + 0x8000u;
        unsigned u1 = __builtin_bit_cast(unsigned, p1) + 0x8000u;
        unsigned u2 = __builtin_bit_cast(unsigned, p2) + 0x8000u;
        unsigned u3 = __builtin_bit_cast(unsigned, p3) + 0x8000u;
        uint2_t d;
        d[0] = __builtin_amdgcn_perm(u1, u0, 0x07060302u);
        d[1] = __builtin_amdgcn_perm(u3, u2, 0x07060302u);
        pf[s4] = __builtin_bit_cast(short4_t, d);
      }
      psum += __shfl_xor(psum, 16, 64);
      psum += __shfl_xor(psum, 32, 64);
      l_i = l_i * alpha + psum;
      m_i = m_new;
      float at[4];
#pragma unroll
      for (int r = 0; r < 4; ++r) at[r] = __shfl(alpha, quad * 4 + r, 64);
#pragma unroll
      for (int f = 0; f < 4; ++f)
#pragma unroll
        for (int r = 0; r < 4; ++r) o[f][r] *= at[r];
#pragma unroll
      for (int f = 0; f < 4; ++f)
#pragma unroll
        for (int s4 = 0; s4 < 4; ++s4) {
          short4_t vf =
              *(const short4_t*)(lv + (f * 16 + lcol) * LDSPITCH + s4 * 16 + quad * 4);
          o[f] = __builtin_amdgcn_mfma_f32_16x16x16bf16_1k(pf[s4], vf, o[f], 0, 0, 0);
        }
    }

    float lt[4];
#pragma unroll
    for (int r = 0; r < 4; ++r) lt[r] = 1.f / __shfl(l_i, quad * 4 + r, 64);
#pragma unroll
    for (int f = 0; f < 4; ++f)
#pragma unroll
      for (int r = 0; r < 4; ++r) {
        int q = q0w + quad * 4 + r;
        int hd = f * 16 + lcol;
        ao[((size_t)b * Sq + q) * (NH * HD) + h * HD + hd] = f2bf(o[f][r] * lt[r]);
      }
  }
}

extern "C" void kernel_launch(void* const* d_in, const int* in_sizes, int n_in,
                              void* d_out, int out_size, void* d_ws, size_t ws_size,
                              hipStream_t stream) {
  const float* x = (const float*)d_in[0];
  const float* Wq = (const float*)d_in[1];
  const float* Wk = (const float*)d_in[2];
  const float* Wv = (const float*)d_in[3];
  const float* Wo = (const float*)d_in[4];
  float* out = (float*)d_out;

  char* ws = (char*)d_ws;
  size_t off = 0;
  auto carve = [&](size_t bytes) {
    void* p = ws + off;
    off += (bytes + 255) & ~(size_t)255;
    return p;
  };
  const size_t xe = (size_t)Bz * Sq * Dm;
  const size_t we = (size_t)Dm * Dm;
  unsigned short* xb = (unsigned short*)carve(xe * 2);
  unsigned short* wqT = (unsigned short*)carve(we * 2);
  unsigned short* wkT = (unsigned short*)carve(we * 2);
  unsigned short* wvT = (unsigned short*)carve(we * 2);
  unsigned short* woT = (unsigned short*)carve(we * 2);
  unsigned short* qb = (unsigned short*)carve(xe * 2);
  unsigned short* kb = (unsigned short*)carve(xe * 2);
  unsigned short* vt = (unsigned short*)carve(xe * 2);
  unsigned short* ao = (unsigned short*)carve(xe * 2);
  (void)ws_size;

  cast_x_kernel<<<xe / 4 / 256, 256, 0, stream>>>(x, xb);
  transpose_w_kernel<<<dim3(16, 16, 4), 256, 0, stream>>>(Wq, Wk, Wv, Wo,
                                                          wqT, wkT, wvT, woT);
  gemm_qkv_kernel<<<dim3(8, 64, 3), 256, 0, stream>>>(xb, wqT, wkT, wvT, qb, kb, vt);
  attn_kernel<<<dim3(16, Bz * NH), 256, 0, stream>>>(qb, kb, vt, ao);
  gemm_out_kernel<<<dim3(8, 64), 256, 0, stream>>>(ao, woT, out);
}

// Round 8
// 293.474 us; speedup vs baseline: 1.5905x; 1.5905x over previous
//
#include <hip/hip_runtime.h>

// SelfAttention: B=4 S=2048 D=1024 H=16 HD=64, causal, fp32 in/out, bf16 MFMA compute.
// R7: consolidation. attn reverted to the R3-exact kernel (64 VGPR, 103us proven).
// R5 (exp2 rewrite) drifted to 68 VGPR -> occupancy cliff (122us); R6's forced
// __launch_bounds__(256,8) made the allocator SPILL to scratch (VGPR=32,
// WRITE_SIZE 16->317MB, 256us). Neither arithmetic "improvement" survives its
// register side effects; attn stays frozen at R3. Merged transpose kept from R6
// (scale=1 everywhere). GEMMs: m97-style (proven).

typedef __attribute__((ext_vector_type(8))) short short8_t;
typedef __attribute__((ext_vector_type(4))) short short4_t;
typedef __attribute__((ext_vector_type(4))) float float4_t;

constexpr int Bz = 4, Sq = 2048, Dm = 1024, NH = 16, HD = 64;
constexpr int LDSPITCH = 72;

#define GLOAD_LDS16(g, l)                                                      \
  __builtin_amdgcn_global_load_lds(                                            \
      (const __attribute__((address_space(1))) unsigned int*)(g),              \
      (__attribute__((address_space(3))) unsigned int*)(l), 16, 0, 0)

__device__ __forceinline__ unsigned short f2bf(float f) {
  unsigned u = __builtin_bit_cast(unsigned, f);
  u += 0x7fffu + ((u >> 16) & 1u);
  return (unsigned short)(u >> 16);
}

__global__ __launch_bounds__(256) void cast_x_kernel(const float* __restrict__ x,
                                                     unsigned short* __restrict__ xb) {
  size_t i = (size_t)blockIdx.x * 256 + threadIdx.x;
  float4 v = ((const float4*)x)[i];
  ushort4 o;
  o.x = f2bf(v.x); o.y = f2bf(v.y); o.z = f2bf(v.z); o.w = f2bf(v.w);
  ((ushort4*)xb)[i] = o;
}

// All four W [K=1024][N=1024] fp32 -> WT [N][K] bf16 in one launch. grid (16,16,4).
__global__ __launch_bounds__(256) void transpose_w_kernel(
    const float* __restrict__ Wq, const float* __restrict__ Wk,
    const float* __restrict__ Wv, const float* __restrict__ Wo,
    unsigned short* __restrict__ wqT, unsigned short* __restrict__ wkT,
    unsigned short* __restrict__ wvT, unsigned short* __restrict__ woT) {
  __shared__ float tile[64][65];
  int zz = blockIdx.z;
  const float* W = zz == 0 ? Wq : (zz == 1 ? Wk : (zz == 2 ? Wv : Wo));
  unsigned short* WT = zz == 0 ? wqT : (zz == 1 ? wkT : (zz == 2 ? wvT : woT));
  int n0 = blockIdx.x * 64, k0 = blockIdx.y * 64;
  int tx = threadIdx.x & 63, ty = threadIdx.x >> 6;
#pragma unroll
  for (int i = 0; i < 16; ++i) {
    int r = i * 4 + ty;
    tile[r][tx] = W[(size_t)(k0 + r) * Dm + n0 + tx];
  }
  __syncthreads();
#pragma unroll
  for (int i = 0; i < 16; ++i) {
    int r = i * 4 + ty;
    WT[(size_t)(n0 + r) * Dm + k0 + tx] = f2bf(tile[tx][r]);
  }
}

// m97-style main loop: 128x128 tile, BK=64, glds width=16, unpadded LDS.
__device__ __forceinline__ void gemm_mainloop(const unsigned short* __restrict__ A,
                                              const unsigned short* __restrict__ BT,
                                              int m0, int n0,
                                              unsigned short* lA, unsigned short* lB,
                                              float4_t acc[4][4]) {
  const int tid = threadIdx.x;
  const int lane = tid & 63, lr = lane & 15, quad = lane >> 4;
  const int wave = tid >> 6;
  const int mw = (wave >> 1) * 64, nw = (wave & 1) * 64;
  const int srow = tid >> 3;
  const int scol = (tid & 7) * 8;
  const unsigned short* ga = A + (size_t)(m0 + srow) * Dm + scol;
  const unsigned short* gb = BT + (size_t)(n0 + srow) * Dm + scol;
  unsigned short* la = lA + tid * 8;
  unsigned short* lb = lB + tid * 8;

  for (int k0 = 0; k0 < Dm; k0 += 64) {
    __syncthreads();
#pragma unroll
    for (int iss = 0; iss < 4; ++iss) {
      GLOAD_LDS16(ga + (size_t)iss * 32 * Dm + k0, la + iss * 32 * 64);
      GLOAD_LDS16(gb + (size_t)iss * 32 * Dm + k0, lb + iss * 32 * 64);
    }
    __syncthreads();
#pragma unroll
    for (int kk = 0; kk < 2; ++kk) {
      short8_t a[4], b[4];
#pragma unroll
      for (int i = 0; i < 4; ++i)
        a[i] = *(const short8_t*)(lA + (mw + i * 16 + lr) * 64 + kk * 32 + quad * 8);
#pragma unroll
      for (int j = 0; j < 4; ++j)
        b[j] = *(const short8_t*)(lB + (nw + j * 16 + lr) * 64 + kk * 32 + quad * 8);
#pragma unroll
      for (int i = 0; i < 4; ++i)
#pragma unroll
        for (int j = 0; j < 4; ++j)
          acc[i][j] = __builtin_amdgcn_mfma_f32_16x16x32_bf16(a[i], b[j], acc[i][j], 0, 0, 0);
    }
  }
}

// QKV projections. Q,K -> [B,H,S,HD]; V -> TRANSPOSED [B,H,HD,S]. grid (8,64,3)
__global__ __launch_bounds__(256) void gemm_qkv_kernel(
    const unsigned short* __restrict__ xb,
    const unsigned short* __restrict__ wqT, const unsigned short* __restrict__ wkT,
    const unsigned short* __restrict__ wvT,
    unsigned short* __restrict__ qb, unsigned short* __restrict__ kb,
    unsigned short* __restrict__ vt) {
  __shared__ unsigned short lA[128 * 64];
  __shared__ unsigned short lB[128 * 64];
  const unsigned short* WT = blockIdx.z == 0 ? wqT : (blockIdx.z == 1 ? wkT : wvT);
  unsigned short* outb = blockIdx.z == 0 ? qb : (blockIdx.z == 1 ? kb : vt);
  bool isV = blockIdx.z == 2;
  int lane = threadIdx.x & 63, wave = threadIdx.x >> 6;
  int lr = lane & 15, quad = lane >> 4;
  int m0 = blockIdx.y * 128, n0 = blockIdx.x * 128;
  int m_base = m0 + (wave >> 1) * 64;
  int n_base = n0 + (wave & 1) * 64;
  float4_t z = {0.f, 0.f, 0.f, 0.f};
  float4_t acc[4][4];
#pragma unroll
  for (int i = 0; i < 4; ++i)
#pragma unroll
    for (int j = 0; j < 4; ++j) acc[i][j] = z;
  gemm_mainloop(xb, WT, m0, n0, lA, lB, acc);
  if (isV) {
#pragma unroll
    for (int i = 0; i < 4; ++i)
#pragma unroll
      for (int j = 0; j < 4; ++j) {
        int m = m_base + i * 16 + quad * 4;
        int n = n_base + j * 16 + lr;
        int b = m >> 11, s = m & (Sq - 1);
        int h = n >> 6, hd = n & (HD - 1);
        ushort4 pk;
        pk.x = f2bf(acc[i][j][0]); pk.y = f2bf(acc[i][j][1]);
        pk.z = f2bf(acc[i][j][2]); pk.w = f2bf(acc[i][j][3]);
        *(ushort4*)(outb + (((size_t)b * NH + h) * HD + hd) * Sq + s) = pk;
      }
  } else {
#pragma unroll
    for (int i = 0; i < 4; ++i)
#pragma unroll
      for (int j = 0; j < 4; ++j)
#pragma unroll
        for (int r = 0; r < 4; ++r) {
          int m = m_base + i * 16 + quad * 4 + r;
          int n = n_base + j * 16 + lr;
          int b = m >> 11, s = m & (Sq - 1);
          int h = n >> 6, hd = n & (HD - 1);
          outb[(((size_t)b * NH + h) * Sq + s) * HD + hd] = f2bf(acc[i][j][r]);
        }
  }
}

// Output projection: ao_bf16 [8192,1024] @ Wo -> fp32 out. grid (8,64)
__global__ __launch_bounds__(256) void gemm_out_kernel(
    const unsigned short* __restrict__ ao, const unsigned short* __restrict__ woT,
    float* __restrict__ out) {
  __shared__ unsigned short lA[128 * 64];
  __shared__ unsigned short lB[128 * 64];
  int lane = threadIdx.x & 63, wave = threadIdx.x >> 6;
  int lr = lane & 15, quad = lane >> 4;
  int m0 = blockIdx.y * 128, n0 = blockIdx.x * 128;
  int m_base = m0 + (wave >> 1) * 64;
  int n_base = n0 + (wave & 1) * 64;
  float4_t z = {0.f, 0.f, 0.f, 0.f};
  float4_t acc[4][4];
#pragma unroll
  for (int i = 0; i < 4; ++i)
#pragma unroll
    for (int j = 0; j < 4; ++j) acc[i][j] = z;
  gemm_mainloop(ao, woT, m0, n0, lA, lB, acc);
#pragma unroll
  for (int i = 0; i < 4; ++i)
#pragma unroll
    for (int j = 0; j < 4; ++j)
#pragma unroll
      for (int r = 0; r < 4; ++r) {
        int m = m_base + i * 16 + quad * 4 + r;
        int n = n_base + j * 16 + lr;
        out[(size_t)m * Dm + n] = acc[i][j][r];
      }
}

// Flash attention — R3-EXACT (proven: 64 VGPR, ~103us, 8 blocks/CU).
// grid (16, B*H), block 256 (4 waves). Block does q-tiles {t, 31-t}.
__global__ __launch_bounds__(256) void attn_kernel(
    const unsigned short* __restrict__ qbuf, const unsigned short* __restrict__ kbuf,
    const unsigned short* __restrict__ vtbuf, unsigned short* __restrict__ ao) {
  __shared__ unsigned short lk[64 * LDSPITCH];
  __shared__ unsigned short lv[64 * LDSPITCH];
  int bh = blockIdx.y;
  int wave = threadIdx.x >> 6, lane = threadIdx.x & 63;
  int lcol = lane & 15, quad = lane >> 4;
  const unsigned short* Q = qbuf + (size_t)bh * Sq * HD;
  const unsigned short* K = kbuf + (size_t)bh * Sq * HD;
  const unsigned short* Vt = vtbuf + (size_t)bh * HD * Sq;
  int b = bh >> 4, h = bh & 15;
  int srow = threadIdx.x >> 2;
  int scol = (threadIdx.x & 3) * 16;
  float4_t z = {0.f, 0.f, 0.f, 0.f};

  for (int half = 0; half < 2; ++half) {
    int ti = half == 0 ? (int)blockIdx.x : 31 - (int)blockIdx.x;
    int q0w = ti * 64 + wave * 16;
    int q_global = q0w + lcol;
    short8_t qf0 = *(const short8_t*)(Q + (size_t)(q0w + lcol) * HD + quad * 8);
    short8_t qf1 = *(const short8_t*)(Q + (size_t)(q0w + lcol) * HD + 32 + quad * 8);
    float m_i = -INFINITY, l_i = 0.f;
    float4_t o[4];
#pragma unroll
    for (int f = 0; f < 4; ++f) o[f] = z;

    int nkt = ti + 1;
    for (int kt = 0; kt < nkt; ++kt) {
      int key0 = kt * 64;
      __syncthreads();
      {
        const unsigned short* kg = K + (size_t)(key0 + srow) * HD + scol;
        const unsigned short* vg = Vt + (size_t)srow * Sq + key0 + scol;
        unsigned short* kl = lk + srow * LDSPITCH + scol;
        unsigned short* vl = lv + srow * LDSPITCH + scol;
        *(short8_t*)(kl) = *(const short8_t*)(kg);
        *(short8_t*)(kl + 8) = *(const short8_t*)(kg + 8);
        *(short8_t*)(vl) = *(const short8_t*)(vg);
        *(short8_t*)(vl + 8) = *(const short8_t*)(vg + 8);
      }
      __syncthreads();

      bool need_mask = (key0 + 63 > q0w);
      float s[16];
      float tmax = -INFINITY;
#pragma unroll
      for (int s4 = 0; s4 < 4; ++s4) {
        short8_t kf0 = *(const short8_t*)(lk + (s4 * 16 + lcol) * LDSPITCH + quad * 8);
        short8_t kf1 = *(const short8_t*)(lk + (s4 * 16 + lcol) * LDSPITCH + 32 + quad * 8);
        float4_t st = z;
        st = __builtin_amdgcn_mfma_f32_16x16x32_bf16(kf0, qf0, st, 0, 0, 0);
        st = __builtin_amdgcn_mfma_f32_16x16x32_bf16(kf1, qf1, st, 0, 0, 0);
#pragma unroll
        for (int r = 0; r < 4; ++r) {
          float v = st[r] * 0.125f;
          if (need_mask && (key0 + s4 * 16 + quad * 4 + r > q_global)) v = -INFINITY;
          s[s4 * 4 + r] = v;
          tmax = fmaxf(tmax, v);
        }
      }
      tmax = fmaxf(tmax, __shfl_xor(tmax, 16, 64));
      tmax = fmaxf(tmax, __shfl_xor(tmax, 32, 64));
      float m_new = fmaxf(m_i, tmax);
      float alpha = __expf(m_i - m_new);
      float psum = 0.f;
      short4_t pf[4];
#pragma unroll
      for (int s4 = 0; s4 < 4; ++s4)
#pragma unroll
        for (int r = 0; r < 4; ++r) {
          float p = __expf(s[s4 * 4 + r] - m_new);
          psum += p;
          pf[s4][r] = (short)f2bf(p);
        }
      psum += __shfl_xor(psum, 16, 64);
      psum += __shfl_xor(psum, 32, 64);
      l_i = l_i * alpha + psum;
      m_i = m_new;
      float at[4];
#pragma unroll
      for (int r = 0; r < 4; ++r) at[r] = __shfl(alpha, quad * 4 + r, 64);
#pragma unroll
      for (int f = 0; f < 4; ++f)
#pragma unroll
        for (int r = 0; r < 4; ++r) o[f][r] *= at[r];
#pragma unroll
      for (int f = 0; f < 4; ++f)
#pragma unroll
        for (int s4 = 0; s4 < 4; ++s4) {
          short4_t vf =
              *(const short4_t*)(lv + (f * 16 + lcol) * LDSPITCH + s4 * 16 + quad * 4);
          o[f] = __builtin_amdgcn_mfma_f32_16x16x16bf16_1k(pf[s4], vf, o[f], 0, 0, 0);
        }
    }

    float lt[4];
#pragma unroll
    for (int r = 0; r < 4; ++r) lt[r] = 1.f / __shfl(l_i, quad * 4 + r, 64);
#pragma unroll
    for (int f = 0; f < 4; ++f)
#pragma unroll
      for (int r = 0; r < 4; ++r) {
        int q = q0w + quad * 4 + r;
        int hd = f * 16 + lcol;
        ao[((size_t)b * Sq + q) * (NH * HD) + h * HD + hd] = f2bf(o[f][r] * lt[r]);
      }
  }
}

extern "C" void kernel_launch(void* const* d_in, const int* in_sizes, int n_in,
                              void* d_out, int out_size, void* d_ws, size_t ws_size,
                              hipStream_t stream) {
  const float* x = (const float*)d_in[0];
  const float* Wq = (const float*)d_in[1];
  const float* Wk = (const float*)d_in[2];
  const float* Wv = (const float*)d_in[3];
  const float* Wo = (const float*)d_in[4];
  float* out = (float*)d_out;

  char* ws = (char*)d_ws;
  size_t off = 0;
  auto carve = [&](size_t bytes) {
    void* p = ws + off;
    off += (bytes + 255) & ~(size_t)255;
    return p;
  };
  const size_t xe = (size_t)Bz * Sq * Dm;
  const size_t we = (size_t)Dm * Dm;
  unsigned short* xb = (unsigned short*)carve(xe * 2);
  unsigned short* wqT = (unsigned short*)carve(we * 2);
  unsigned short* wkT = (unsigned short*)carve(we * 2);
  unsigned short* wvT = (unsigned short*)carve(we * 2);
  unsigned short* woT = (unsigned short*)carve(we * 2);
  unsigned short* qb = (unsigned short*)carve(xe * 2);
  unsigned short* kb = (unsigned short*)carve(xe * 2);
  unsigned short* vt = (unsigned short*)carve(xe * 2);
  unsigned short* ao = (unsigned short*)carve(xe * 2);
  (void)ws_size;

  cast_x_kernel<<<xe / 4 / 256, 256, 0, stream>>>(x, xb);
  transpose_w_kernel<<<dim3(16, 16, 4), 256, 0, stream>>>(Wq, Wk, Wv, Wo,
                                                          wqT, wkT, wvT, woT);
  gemm_qkv_kernel<<<dim3(8, 64, 3), 256, 0, stream>>>(xb, wqT, wkT, wvT, qb, kb, vt);
  attn_kernel<<<dim3(16, Bz * NH), 256, 0, stream>>>(qb, kb, vt, ao);
  gemm_out_kernel<<<dim3(8, 64), 256, 0, stream>>>(ao, woT, out);
}

// Round 9
// 290.882 us; speedup vs baseline: 1.6047x; 1.0089x over previous
//
#include <hip/hip_runtime.h>

// SelfAttention: B=4 S=2048 D=1024 H=16 HD=64, causal, fp32 in/out, bf16 MFMA compute.
// R8->R9: attn occupancy fix via GRID only (inner loop R3-exact, zero register
// risk). Paired grid (16,64)=1024 blocks = 4 blocks/CU though VGPR/LDS allow 8;
// VALU (the bottleneck) only 67% busy. New grid (64,32): one 64-row q-tile per
// block, 2048 blocks = exactly 8/CU co-resident. Tile index in blockIdx.Y so
// round-robin dispatch gives each CU tiles at stride 4 (work sums 120-144 steps,
// +-9%) — tile-in-X (R4) gives a CU 8x the SAME tile (8..256 steps, ~2x makespan).

typedef __attribute__((ext_vector_type(8))) short short8_t;
typedef __attribute__((ext_vector_type(4))) short short4_t;
typedef __attribute__((ext_vector_type(4))) float float4_t;

constexpr int Bz = 4, Sq = 2048, Dm = 1024, NH = 16, HD = 64;
constexpr int LDSPITCH = 72;

#define GLOAD_LDS16(g, l)                                                      \
  __builtin_amdgcn_global_load_lds(                                            \
      (const __attribute__((address_space(1))) unsigned int*)(g),              \
      (__attribute__((address_space(3))) unsigned int*)(l), 16, 0, 0)

__device__ __forceinline__ unsigned short f2bf(float f) {
  unsigned u = __builtin_bit_cast(unsigned, f);
  u += 0x7fffu + ((u >> 16) & 1u);
  return (unsigned short)(u >> 16);
}

__global__ __launch_bounds__(256) void cast_x_kernel(const float* __restrict__ x,
                                                     unsigned short* __restrict__ xb) {
  size_t i = (size_t)blockIdx.x * 256 + threadIdx.x;
  float4 v = ((const float4*)x)[i];
  ushort4 o;
  o.x = f2bf(v.x); o.y = f2bf(v.y); o.z = f2bf(v.z); o.w = f2bf(v.w);
  ((ushort4*)xb)[i] = o;
}

// All four W [K=1024][N=1024] fp32 -> WT [N][K] bf16 in one launch. grid (16,16,4).
__global__ __launch_bounds__(256) void transpose_w_kernel(
    const float* __restrict__ Wq, const float* __restrict__ Wk,
    const float* __restrict__ Wv, const float* __restrict__ Wo,
    unsigned short* __restrict__ wqT, unsigned short* __restrict__ wkT,
    unsigned short* __restrict__ wvT, unsigned short* __restrict__ woT) {
  __shared__ float tile[64][65];
  int zz = blockIdx.z;
  const float* W = zz == 0 ? Wq : (zz == 1 ? Wk : (zz == 2 ? Wv : Wo));
  unsigned short* WT = zz == 0 ? wqT : (zz == 1 ? wkT : (zz == 2 ? wvT : woT));
  int n0 = blockIdx.x * 64, k0 = blockIdx.y * 64;
  int tx = threadIdx.x & 63, ty = threadIdx.x >> 6;
#pragma unroll
  for (int i = 0; i < 16; ++i) {
    int r = i * 4 + ty;
    tile[r][tx] = W[(size_t)(k0 + r) * Dm + n0 + tx];
  }
  __syncthreads();
#pragma unroll
  for (int i = 0; i < 16; ++i) {
    int r = i * 4 + ty;
    WT[(size_t)(n0 + r) * Dm + k0 + tx] = f2bf(tile[tx][r]);
  }
}

// m97-style main loop: 128x128 tile, BK=64, glds width=16, unpadded LDS.
__device__ __forceinline__ void gemm_mainloop(const unsigned short* __restrict__ A,
                                              const unsigned short* __restrict__ BT,
                                              int m0, int n0,
                                              unsigned short* lA, unsigned short* lB,
                                              float4_t acc[4][4]) {
  const int tid = threadIdx.x;
  const int lane = tid & 63, lr = lane & 15, quad = lane >> 4;
  const int wave = tid >> 6;
  const int mw = (wave >> 1) * 64, nw = (wave & 1) * 64;
  const int srow = tid >> 3;
  const int scol = (tid & 7) * 8;
  const unsigned short* ga = A + (size_t)(m0 + srow) * Dm + scol;
  const unsigned short* gb = BT + (size_t)(n0 + srow) * Dm + scol;
  unsigned short* la = lA + tid * 8;
  unsigned short* lb = lB + tid * 8;

  for (int k0 = 0; k0 < Dm; k0 += 64) {
    __syncthreads();
#pragma unroll
    for (int iss = 0; iss < 4; ++iss) {
      GLOAD_LDS16(ga + (size_t)iss * 32 * Dm + k0, la + iss * 32 * 64);
      GLOAD_LDS16(gb + (size_t)iss * 32 * Dm + k0, lb + iss * 32 * 64);
    }
    __syncthreads();
#pragma unroll
    for (int kk = 0; kk < 2; ++kk) {
      short8_t a[4], b[4];
#pragma unroll
      for (int i = 0; i < 4; ++i)
        a[i] = *(const short8_t*)(lA + (mw + i * 16 + lr) * 64 + kk * 32 + quad * 8);
#pragma unroll
      for (int j = 0; j < 4; ++j)
        b[j] = *(const short8_t*)(lB + (nw + j * 16 + lr) * 64 + kk * 32 + quad * 8);
#pragma unroll
      for (int i = 0; i < 4; ++i)
#pragma unroll
        for (int j = 0; j < 4; ++j)
          acc[i][j] = __builtin_amdgcn_mfma_f32_16x16x32_bf16(a[i], b[j], acc[i][j], 0, 0, 0);
    }
  }
}

// QKV projections. Q,K -> [B,H,S,HD]; V -> TRANSPOSED [B,H,HD,S]. grid (8,64,3)
__global__ __launch_bounds__(256) void gemm_qkv_kernel(
    const unsigned short* __restrict__ xb,
    const unsigned short* __restrict__ wqT, const unsigned short* __restrict__ wkT,
    const unsigned short* __restrict__ wvT,
    unsigned short* __restrict__ qb, unsigned short* __restrict__ kb,
    unsigned short* __restrict__ vt) {
  __shared__ unsigned short lA[128 * 64];
  __shared__ unsigned short lB[128 * 64];
  const unsigned short* WT = blockIdx.z == 0 ? wqT : (blockIdx.z == 1 ? wkT : wvT);
  unsigned short* outb = blockIdx.z == 0 ? qb : (blockIdx.z == 1 ? kb : vt);
  bool isV = blockIdx.z == 2;
  int lane = threadIdx.x & 63, wave = threadIdx.x >> 6;
  int lr = lane & 15, quad = lane >> 4;
  int m0 = blockIdx.y * 128, n0 = blockIdx.x * 128;
  int m_base = m0 + (wave >> 1) * 64;
  int n_base = n0 + (wave & 1) * 64;
  float4_t z = {0.f, 0.f, 0.f, 0.f};
  float4_t acc[4][4];
#pragma unroll
  for (int i = 0; i < 4; ++i)
#pragma unroll
    for (int j = 0; j < 4; ++j) acc[i][j] = z;
  gemm_mainloop(xb, WT, m0, n0, lA, lB, acc);
  if (isV) {
#pragma unroll
    for (int i = 0; i < 4; ++i)
#pragma unroll
      for (int j = 0; j < 4; ++j) {
        int m = m_base + i * 16 + quad * 4;
        int n = n_base + j * 16 + lr;
        int b = m >> 11, s = m & (Sq - 1);
        int h = n >> 6, hd = n & (HD - 1);
        ushort4 pk;
        pk.x = f2bf(acc[i][j][0]); pk.y = f2bf(acc[i][j][1]);
        pk.z = f2bf(acc[i][j][2]); pk.w = f2bf(acc[i][j][3]);
        *(ushort4*)(outb + (((size_t)b * NH + h) * HD + hd) * Sq + s) = pk;
      }
  } else {
#pragma unroll
    for (int i = 0; i < 4; ++i)
#pragma unroll
      for (int j = 0; j < 4; ++j)
#pragma unroll
        for (int r = 0; r < 4; ++r) {
          int m = m_base + i * 16 + quad * 4 + r;
          int n = n_base + j * 16 + lr;
          int b = m >> 11, s = m & (Sq - 1);
          int h = n >> 6, hd = n & (HD - 1);
          outb[(((size_t)b * NH + h) * Sq + s) * HD + hd] = f2bf(acc[i][j][r]);
        }
  }
}

// Output projection: ao_bf16 [8192,1024] @ Wo -> fp32 out. grid (8,64)
__global__ __launch_bounds__(256) void gemm_out_kernel(
    const unsigned short* __restrict__ ao, const unsigned short* __restrict__ woT,
    float* __restrict__ out) {
  __shared__ unsigned short lA[128 * 64];
  __shared__ unsigned short lB[128 * 64];
  int lane = threadIdx.x & 63, wave = threadIdx.x >> 6;
  int lr = lane & 15, quad = lane >> 4;
  int m0 = blockIdx.y * 128, n0 = blockIdx.x * 128;
  int m_base = m0 + (wave >> 1) * 64;
  int n_base = n0 + (wave & 1) * 64;
  float4_t z = {0.f, 0.f, 0.f, 0.f};
  float4_t acc[4][4];
#pragma unroll
  for (int i = 0; i < 4; ++i)
#pragma unroll
    for (int j = 0; j < 4; ++j) acc[i][j] = z;
  gemm_mainloop(ao, woT, m0, n0, lA, lB, acc);
#pragma unroll
  for (int i = 0; i < 4; ++i)
#pragma unroll
    for (int j = 0; j < 4; ++j)
#pragma unroll
      for (int r = 0; r < 4; ++r) {
        int m = m_base + i * 16 + quad * 4 + r;
        int n = n_base + j * 16 + lr;
        out[(size_t)m * Dm + n] = acc[i][j][r];
      }
}

// Flash attention — R3-exact inner loop; grid (B*H, 32), one 64-row q-tile per
// block, ti = 31 - blockIdx.y (big tiles dispatch first).
__global__ __launch_bounds__(256) void attn_kernel(
    const unsigned short* __restrict__ qbuf, const unsigned short* __restrict__ kbuf,
    const unsigned short* __restrict__ vtbuf, unsigned short* __restrict__ ao) {
  __shared__ unsigned short lk[64 * LDSPITCH];
  __shared__ unsigned short lv[64 * LDSPITCH];
  int bh = blockIdx.x;
  int ti = 31 - (int)blockIdx.y;
  int wave = threadIdx.x >> 6, lane = threadIdx.x & 63;
  int lcol = lane & 15, quad = lane >> 4;
  const unsigned short* Q = qbuf + (size_t)bh * Sq * HD;
  const unsigned short* K = kbuf + (size_t)bh * Sq * HD;
  const unsigned short* Vt = vtbuf + (size_t)bh * HD * Sq;
  int b = bh >> 4, h = bh & 15;
  int srow = threadIdx.x >> 2;
  int scol = (threadIdx.x & 3) * 16;
  float4_t z = {0.f, 0.f, 0.f, 0.f};

  int q0w = ti * 64 + wave * 16;
  int q_global = q0w + lcol;
  short8_t qf0 = *(const short8_t*)(Q + (size_t)(q0w + lcol) * HD + quad * 8);
  short8_t qf1 = *(const short8_t*)(Q + (size_t)(q0w + lcol) * HD + 32 + quad * 8);
  float m_i = -INFINITY, l_i = 0.f;
  float4_t o[4];
#pragma unroll
  for (int f = 0; f < 4; ++f) o[f] = z;

  int nkt = ti + 1;
  for (int kt = 0; kt < nkt; ++kt) {
    int key0 = kt * 64;
    __syncthreads();
    {
      const unsigned short* kg = K + (size_t)(key0 + srow) * HD + scol;
      const unsigned short* vg = Vt + (size_t)srow * Sq + key0 + scol;
      unsigned short* kl = lk + srow * LDSPITCH + scol;
      unsigned short* vl = lv + srow * LDSPITCH + scol;
      *(short8_t*)(kl) = *(const short8_t*)(kg);
      *(short8_t*)(kl + 8) = *(const short8_t*)(kg + 8);
      *(short8_t*)(vl) = *(const short8_t*)(vg);
      *(short8_t*)(vl + 8) = *(const short8_t*)(vg + 8);
    }
    __syncthreads();

    bool need_mask = (key0 + 63 > q0w);
    float s[16];
    float tmax = -INFINITY;
#pragma unroll
    for (int s4 = 0; s4 < 4; ++s4) {
      short8_t kf0 = *(const short8_t*)(lk + (s4 * 16 + lcol) * LDSPITCH + quad * 8);
      short8_t kf1 = *(const short8_t*)(lk + (s4 * 16 + lcol) * LDSPITCH + 32 + quad * 8);
      float4_t st = z;
      st = __builtin_amdgcn_mfma_f32_16x16x32_bf16(kf0, qf0, st, 0, 0, 0);
      st = __builtin_amdgcn_mfma_f32_16x16x32_bf16(kf1, qf1, st, 0, 0, 0);
#pragma unroll
      for (int r = 0; r < 4; ++r) {
        float v = st[r] * 0.125f;
        if (need_mask && (key0 + s4 * 16 + quad * 4 + r > q_global)) v = -INFINITY;
        s[s4 * 4 + r] = v;
        tmax = fmaxf(tmax, v);
      }
    }
    tmax = fmaxf(tmax, __shfl_xor(tmax, 16, 64));
    tmax = fmaxf(tmax, __shfl_xor(tmax, 32, 64));
    float m_new = fmaxf(m_i, tmax);
    float alpha = __expf(m_i - m_new);
    float psum = 0.f;
    short4_t pf[4];
#pragma unroll
    for (int s4 = 0; s4 < 4; ++s4)
#pragma unroll
      for (int r = 0; r < 4; ++r) {
        float p = __expf(s[s4 * 4 + r] - m_new);
        psum += p;
        pf[s4][r] = (short)f2bf(p);
      }
    psum += __shfl_xor(psum, 16, 64);
    psum += __shfl_xor(psum, 32, 64);
    l_i = l_i * alpha + psum;
    m_i = m_new;
    float at[4];
#pragma unroll
    for (int r = 0; r < 4; ++r) at[r] = __shfl(alpha, quad * 4 + r, 64);
#pragma unroll
    for (int f = 0; f < 4; ++f)
#pragma unroll
      for (int r = 0; r < 4; ++r) o[f][r] *= at[r];
#pragma unroll
    for (int f = 0; f < 4; ++f)
#pragma unroll
      for (int s4 = 0; s4 < 4; ++s4) {
        short4_t vf =
            *(const short4_t*)(lv + (f * 16 + lcol) * LDSPITCH + s4 * 16 + quad * 4);
        o[f] = __builtin_amdgcn_mfma_f32_16x16x16bf16_1k(pf[s4], vf, o[f], 0, 0, 0);
      }
  }

  float lt[4];
#pragma unroll
  for (int r = 0; r < 4; ++r) lt[r] = 1.f / __shfl(l_i, quad * 4 + r, 64);
#pragma unroll
  for (int f = 0; f < 4; ++f)
#pragma unroll
    for (int r = 0; r < 4; ++r) {
      int q = q0w + quad * 4 + r;
      int hd = f * 16 + lcol;
      ao[((size_t)b * Sq + q) * (NH * HD) + h * HD + hd] = f2bf(o[f][r] * lt[r]);
    }
}

extern "C" void kernel_launch(void* const* d_in, const int* in_sizes, int n_in,
                              void* d_out, int out_size, void* d_ws, size_t ws_size,
                              hipStream_t stream) {
  const float* x = (const float*)d_in[0];
  const float* Wq = (const float*)d_in[1];
  const float* Wk = (const float*)d_in[2];
  const float* Wv = (const float*)d_in[3];
  const float* Wo = (const float*)d_in[4];
  float* out = (float*)d_out;

  char* ws = (char*)d_ws;
  size_t off = 0;
  auto carve = [&](size_t bytes) {
    void* p = ws + off;
    off += (bytes + 255) & ~(size_t)255;
    return p;
  };
  const size_t xe = (size_t)Bz * Sq * Dm;
  const size_t we = (size_t)Dm * Dm;
  unsigned short* xb = (unsigned short*)carve(xe * 2);
  unsigned short* wqT = (unsigned short*)carve(we * 2);
  unsigned short* wkT = (unsigned short*)carve(we * 2);
  unsigned short* wvT = (unsigned short*)carve(we * 2);
  unsigned short* woT = (unsigned short*)carve(we * 2);
  unsigned short* qb = (unsigned short*)carve(xe * 2);
  unsigned short* kb = (unsigned short*)carve(xe * 2);
  unsigned short* vt = (unsigned short*)carve(xe * 2);
  unsigned short* ao = (unsigned short*)carve(xe * 2);
  (void)ws_size;

  cast_x_kernel<<<xe / 4 / 256, 256, 0, stream>>>(x, xb);
  transpose_w_kernel<<<dim3(16, 16, 4), 256, 0, stream>>>(Wq, Wk, Wv, Wo,
                                                          wqT, wkT, wvT, woT);
  gemm_qkv_kernel<<<dim3(8, 64, 3), 256, 0, stream>>>(xb, wqT, wkT, wvT, qb, kb, vt);
  attn_kernel<<<dim3(Bz * NH, 32), 256, 0, stream>>>(qb, kb, vt, ao);
  gemm_out_kernel<<<dim3(8, 64), 256, 0, stream>>>(ao, woT, out);
}